// Round 15
// baseline (121.219 us; speedup 1.0000x reference)
//
#include <hip/hip_runtime.h>
#include <hip/hip_fp16.h>

#define KNB 31
#define CH 64
#define TEMP_INV 10.0f   // 1 / temperature(0.1)

typedef _Float16 h2 __attribute__((ext_vector_type(2)));
typedef float f2 __attribute__((ext_vector_type(2)));

// ---------------------------------------------------------------------------
// ws layout (chunked fp8 path):
//   bytes [0, 16)                     : double ws[2] (sum(loss*mask), sum(mask))
//   bytes [256, 256+N*64)             : fp8 e4m3 feature table
//   bytes [256+N*64, 256+N*64+N*16)   : float4 state[N] {m, se, sp, cnt}
//
// R13 lesson: NO __threadfence in hot kernels (per-block device fence = L2
// writeback x1563 -> +45% dur at identical FETCH). Phase barrier between
// chunk passes = the kernel launch boundary itself.
// ---------------------------------------------------------------------------

__global__ void ch_init_ws(double* __restrict__ ws) {
    ws[0] = 0.0;
    ws[1] = 0.0;
}

// features f32 -> fp8 e4m3 table (8 floats -> 8 bytes per thread); zeroes ws.
__global__ __launch_bounds__(256) void ch_cvt8(
    const float* __restrict__ in, unsigned char* __restrict__ out,
    double* __restrict__ ws, int total8)
{
    const int idx = blockIdx.x * blockDim.x + threadIdx.x;
    if (idx == 0) { ws[0] = 0.0; ws[1] = 0.0; }
    if (idx >= total8) return;
    const float4* ip = reinterpret_cast<const float4*>(in) + (size_t)idx * 2;
    const float4 a = ip[0];
    const float4 b = ip[1];
    unsigned lo = 0u, hi = 0u;
    lo = __builtin_amdgcn_cvt_pk_fp8_f32(a.x, a.y, lo, false);
    lo = __builtin_amdgcn_cvt_pk_fp8_f32(a.z, a.w, lo, true);
    hi = __builtin_amdgcn_cvt_pk_fp8_f32(b.x, b.y, hi, false);
    hi = __builtin_amdgcn_cvt_pk_fp8_f32(b.z, b.w, hi, true);
    uint2 o; o.x = lo; o.y = hi;
    reinterpret_cast<uint2*>(out)[idx] = o;
}

// ---------------------------------------------------------------------------
// Pass A: neighbors with nj < nhalf (chunk 0, 3.2 MB -> fits per-XCD L2).
// R8-exact loop body under a quad-uniform chunk guard; writes online-softmax
// state to ws. No LDS, no reduction, no fence.
// ---------------------------------------------------------------------------
__global__ __launch_bounds__(256) void ch_mainA(
    const unsigned char* __restrict__ tab8,
    const int*           __restrict__ labels,
    const int*           __restrict__ nidx,
    float4*              __restrict__ state,
    int n, int nhalf)
{
    const int t   = threadIdx.x;
    const int i   = blockIdx.x * (256 / 4) + (t >> 2);
    const int sub = t & 3;
    if (i >= n) return;

    float fA[16];
    {
        union { uint4 u; unsigned w[4]; } Au;
        Au.u = reinterpret_cast<const uint4*>(tab8 + (size_t)i * CH)[sub];
        #pragma unroll
        for (int q = 0; q < 4; ++q) {
            const f2 p0 = __builtin_amdgcn_cvt_pk_f32_fp8(Au.w[q], false);
            const f2 p1 = __builtin_amdgcn_cvt_pk_f32_fp8(Au.w[q], true);
            fA[4 * q + 0] = p0[0]; fA[4 * q + 1] = p0[1];
            fA[4 * q + 2] = p1[0]; fA[4 * q + 3] = p1[1];
        }
    }

    const int lab = labels[i];
    const int* nrow = nidx + (size_t)i * KNB;

    float m  = -1e30f;
    float se = 0.0f;
    float sp = 0.0f;
    int   cnt = 0;

    #pragma unroll 4
    for (int j = 0; j < KNB; ++j) {
        const int nj = nrow[j];                       // quad-broadcast
        if (nj < nhalf) {                             // quad-uniform guard
            union { uint4 u; unsigned w[4]; } Bu;
            Bu.u = reinterpret_cast<const uint4*>(tab8 + (size_t)nj * CH)[sub];

            float s = 0.0f;
            #pragma unroll
            for (int q = 0; q < 4; ++q) {
                const f2 p0 = __builtin_amdgcn_cvt_pk_f32_fp8(Bu.w[q], false);
                const f2 p1 = __builtin_amdgcn_cvt_pk_f32_fp8(Bu.w[q], true);
                float d;
                d = fA[4 * q + 0] - p0[0]; s = fmaf(d, d, s);
                d = fA[4 * q + 1] - p0[1]; s = fmaf(d, d, s);
                d = fA[4 * q + 2] - p1[0]; s = fmaf(d, d, s);
                d = fA[4 * q + 3] - p1[1]; s = fmaf(d, d, s);
            }
            s += __shfl_xor(s, 1);
            s += __shfl_xor(s, 2);

            const float l = -(sqrtf(s) + 1e-8f);
            const bool pm = (labels[nj] == lab);
            cnt += pm ? 1 : 0;

            if (l > m) {
                const float r = __expf((m - l) * TEMP_INV);
                se *= r; sp *= r; m = l;
            }
            const float e = __expf((l - m) * TEMP_INV);
            se += e;
            if (pm) sp += e;
        }
    }

    if (sub == 0)
        state[i] = make_float4(m, se, sp, (float)cnt);
}

// ---------------------------------------------------------------------------
// Pass B: neighbors with nj >= nhalf (chunk 1). Resumes the online state
// (order-invariant continuation, R11-validated), finishes loss, block-reduces.
// No fence; finalize is a separate 1-thread kernel.
// ---------------------------------------------------------------------------
__global__ __launch_bounds__(256) void ch_mainB(
    const unsigned char* __restrict__ tab8,
    const int*           __restrict__ labels,
    const int*           __restrict__ nidx,
    const float4*        __restrict__ state,
    double*              __restrict__ ws,
    int n, int nhalf)
{
    const int t   = threadIdx.x;
    const int i   = blockIdx.x * (256 / 4) + (t >> 2);
    const int sub = t & 3;

    float loss_w = 0.0f;
    float pm_f   = 0.0f;

    if (i < n) {
        float fA[16];
        {
            union { uint4 u; unsigned w[4]; } Au;
            Au.u = reinterpret_cast<const uint4*>(tab8 + (size_t)i * CH)[sub];
            #pragma unroll
            for (int q = 0; q < 4; ++q) {
                const f2 p0 = __builtin_amdgcn_cvt_pk_f32_fp8(Au.w[q], false);
                const f2 p1 = __builtin_amdgcn_cvt_pk_f32_fp8(Au.w[q], true);
                fA[4 * q + 0] = p0[0]; fA[4 * q + 1] = p0[1];
                fA[4 * q + 2] = p1[0]; fA[4 * q + 3] = p1[1];
            }
        }

        const int lab = labels[i];
        const int* nrow = nidx + (size_t)i * KNB;

        const float4 st = state[i];                   // quad-broadcast
        float m  = st.x;
        float se = st.y;
        float sp = st.z;
        int   cnt = (int)st.w;

        #pragma unroll 4
        for (int j = 0; j < KNB; ++j) {
            const int nj = nrow[j];                   // quad-broadcast
            if (nj >= nhalf) {                        // quad-uniform guard
                union { uint4 u; unsigned w[4]; } Bu;
                Bu.u = reinterpret_cast<const uint4*>(tab8 + (size_t)nj * CH)[sub];

                float s = 0.0f;
                #pragma unroll
                for (int q = 0; q < 4; ++q) {
                    const f2 p0 = __builtin_amdgcn_cvt_pk_f32_fp8(Bu.w[q], false);
                    const f2 p1 = __builtin_amdgcn_cvt_pk_f32_fp8(Bu.w[q], true);
                    float d;
                    d = fA[4 * q + 0] - p0[0]; s = fmaf(d, d, s);
                    d = fA[4 * q + 1] - p0[1]; s = fmaf(d, d, s);
                    d = fA[4 * q + 2] - p1[0]; s = fmaf(d, d, s);
                    d = fA[4 * q + 3] - p1[1]; s = fmaf(d, d, s);
                }
                s += __shfl_xor(s, 1);
                s += __shfl_xor(s, 2);

                const float l = -(sqrtf(s) + 1e-8f);
                const bool pm = (labels[nj] == lab);
                cnt += pm ? 1 : 0;

                if (l > m) {
                    const float r = __expf((m - l) * TEMP_INV);
                    se *= r; sp *= r; m = l;
                }
                const float e = __expf((l - m) * TEMP_INV);
                se += e;
                if (pm) sp += e;
            }
        }

        if (sub == 0 && cnt > 0 && cnt < KNB) {
            loss_w = -logf(sp / se + 1e-8f);
            pm_f   = 1.0f;
        }
    }

    __shared__ float s_l[256];
    __shared__ float s_c[256];
    s_l[t] = loss_w;
    s_c[t] = pm_f;
    __syncthreads();
    #pragma unroll
    for (int off = 128; off > 0; off >>= 1) {
        if (t < off) {
            s_l[t] += s_l[t + off];
            s_c[t] += s_c[t + off];
        }
        __syncthreads();
    }
    if (t == 0) {
        atomicAdd(ws,     (double)s_l[0]);
        atomicAdd(ws + 1, (double)s_c[0]);
    }
}

// ---------------------------------------------------------------------------
// R14 single-pass fp8 main (proven 69.5 us) — fallback if ws can't hold state.
// ---------------------------------------------------------------------------
__global__ __launch_bounds__(256) void ch_main8q(
    const unsigned char* __restrict__ tab8,
    const int*           __restrict__ labels,
    const int*           __restrict__ nidx,
    double*              __restrict__ ws,
    int n)
{
    const int t   = threadIdx.x;
    const int i   = blockIdx.x * (256 / 4) + (t >> 2);
    const int sub = t & 3;

    float loss_w = 0.0f;
    float pm_f   = 0.0f;

    if (i < n) {
        float fA[16];
        {
            union { uint4 u; unsigned w[4]; } Au;
            Au.u = reinterpret_cast<const uint4*>(tab8 + (size_t)i * CH)[sub];
            #pragma unroll
            for (int q = 0; q < 4; ++q) {
                const f2 p0 = __builtin_amdgcn_cvt_pk_f32_fp8(Au.w[q], false);
                const f2 p1 = __builtin_amdgcn_cvt_pk_f32_fp8(Au.w[q], true);
                fA[4 * q + 0] = p0[0]; fA[4 * q + 1] = p0[1];
                fA[4 * q + 2] = p1[0]; fA[4 * q + 3] = p1[1];
            }
        }

        const int lab = labels[i];
        const int* nrow = nidx + (size_t)i * KNB;

        float m  = -1e30f;
        float se = 0.0f;
        float sp = 0.0f;
        int   cnt = 0;

        #pragma unroll 4
        for (int j = 0; j < KNB; ++j) {
            const int nj = nrow[j];

            union { uint4 u; unsigned w[4]; } Bu;
            Bu.u = reinterpret_cast<const uint4*>(tab8 + (size_t)nj * CH)[sub];

            float s = 0.0f;
            #pragma unroll
            for (int q = 0; q < 4; ++q) {
                const f2 p0 = __builtin_amdgcn_cvt_pk_f32_fp8(Bu.w[q], false);
                const f2 p1 = __builtin_amdgcn_cvt_pk_f32_fp8(Bu.w[q], true);
                float d;
                d = fA[4 * q + 0] - p0[0]; s = fmaf(d, d, s);
                d = fA[4 * q + 1] - p0[1]; s = fmaf(d, d, s);
                d = fA[4 * q + 2] - p1[0]; s = fmaf(d, d, s);
                d = fA[4 * q + 3] - p1[1]; s = fmaf(d, d, s);
            }
            s += __shfl_xor(s, 1);
            s += __shfl_xor(s, 2);

            const float l = -(sqrtf(s) + 1e-8f);
            const bool pm = (labels[nj] == lab);
            cnt += pm ? 1 : 0;

            if (l > m) {
                const float r = __expf((m - l) * TEMP_INV);
                se *= r; sp *= r; m = l;
            }
            const float e = __expf((l - m) * TEMP_INV);
            se += e;
            if (pm) sp += e;
        }

        if (sub == 0 && cnt > 0 && cnt < KNB) {
            loss_w = -logf(sp / se + 1e-8f);
            pm_f   = 1.0f;
        }
    }

    __shared__ float s_l[256];
    __shared__ float s_c[256];
    s_l[t] = loss_w;
    s_c[t] = pm_f;
    __syncthreads();
    #pragma unroll
    for (int off = 128; off > 0; off >>= 1) {
        if (t < off) {
            s_l[t] += s_l[t + off];
            s_c[t] += s_c[t + off];
        }
        __syncthreads();
    }
    if (t == 0) {
        atomicAdd(ws,     (double)s_l[0]);
        atomicAdd(ws + 1, (double)s_c[0]);
    }
}

// ---------------------------------------------------------------------------
// f32 direct fallback (R2-exact) — only if ws can't hold the fp8 table.
// ---------------------------------------------------------------------------
__global__ __launch_bounds__(256) void ch_main4f(
    const float* __restrict__ feat,
    const int*   __restrict__ labels,
    const int*   __restrict__ nidx,
    double*      __restrict__ ws,
    int n)
{
    const int t   = threadIdx.x;
    const int i   = blockIdx.x * (256 / 4) + (t >> 2);
    const int sub = t & 3;

    float loss_w = 0.0f;
    float pm_f   = 0.0f;

    if (i < n) {
        float f[16];
        const float4* ap = reinterpret_cast<const float4*>(feat + (size_t)i * CH + sub * 16);
        #pragma unroll
        for (int q = 0; q < 4; ++q) {
            const float4 v = ap[q];
            f[4 * q] = v.x; f[4 * q + 1] = v.y; f[4 * q + 2] = v.z; f[4 * q + 3] = v.w;
        }
        const int lab = labels[i];
        float m = -1e30f, se = 0.0f, sp = 0.0f;
        int cnt = 0;
        #pragma unroll 2
        for (int j = 0; j < KNB; ++j) {
            const int nj = nidx[(size_t)i * KNB + j];
            const float4* bp = reinterpret_cast<const float4*>(feat + (size_t)nj * CH + sub * 16);
            float s = 0.0f;
            #pragma unroll
            for (int q = 0; q < 4; ++q) {
                const float4 v = bp[q];
                float d;
                d = f[4 * q]     - v.x; s += d * d;
                d = f[4 * q + 1] - v.y; s += d * d;
                d = f[4 * q + 2] - v.z; s += d * d;
                d = f[4 * q + 3] - v.w; s += d * d;
            }
            s += __shfl_xor(s, 1);
            s += __shfl_xor(s, 2);
            const float l = -(sqrtf(s) + 1e-8f);
            const bool pm = (labels[nj] == lab);
            cnt += pm ? 1 : 0;
            if (l > m) {
                const float r = __expf((m - l) * TEMP_INV);
                se *= r; sp *= r; m = l;
            }
            const float e = __expf((l - m) * TEMP_INV);
            se += e;
            if (pm) sp += e;
        }
        if (sub == 0 && cnt > 0 && cnt < KNB) {
            loss_w = -logf(sp / se + 1e-8f);
            pm_f   = 1.0f;
        }
    }

    __shared__ float s_l[256];
    __shared__ float s_c[256];
    s_l[t] = loss_w;
    s_c[t] = pm_f;
    __syncthreads();
    #pragma unroll
    for (int off = 128; off > 0; off >>= 1) {
        if (t < off) {
            s_l[t] += s_l[t + off];
            s_c[t] += s_c[t + off];
        }
        __syncthreads();
    }
    if (t == 0) {
        atomicAdd(ws,     (double)s_l[0]);
        atomicAdd(ws + 1, (double)s_c[0]);
    }
}

__global__ void ch_finalize(const double* __restrict__ ws, float* __restrict__ out) {
    double c = ws[1];
    if (c < 1.0) c = 1.0;
    out[0] = (float)(ws[0] / c);   // WEIGHT = 1.0
}

extern "C" void kernel_launch(void* const* d_in, const int* in_sizes, int n_in,
                              void* d_out, int out_size, void* d_ws, size_t ws_size,
                              hipStream_t stream) {
    const float* feat   = (const float*)d_in[0];
    const int*   labels = (const int*)d_in[1];
    const int*   nidx   = (const int*)d_in[2];
    float*       out    = (float*)d_out;
    double*      ws     = (double*)d_ws;

    const int n = in_sizes[1];                 // N = 100000
    const int total8 = n * CH / 8;
    const int blocks = (n + 63) / 64;          // 64 points per 256-thread block

    const size_t tab_bytes   = (size_t)n * CH;         // fp8 table
    const size_t state_bytes = (size_t)n * 16;         // float4 per point

    if (ws_size >= 256 + tab_bytes + state_bytes) {    // chunked 2-pass fp8
        unsigned char* tab = (unsigned char*)d_ws + 256;
        float4* state = reinterpret_cast<float4*>((char*)d_ws + 256 + tab_bytes);
        const int nhalf = n / 2;
        ch_cvt8<<<(total8 + 255) / 256, 256, 0, stream>>>(feat, tab, ws, total8);
        ch_mainA<<<blocks, 256, 0, stream>>>(tab, labels, nidx, state, n, nhalf);
        ch_mainB<<<blocks, 256, 0, stream>>>(tab, labels, nidx, state, ws, n, nhalf);
        ch_finalize<<<1, 1, 0, stream>>>(ws, out);
        return;
    }

    if (ws_size >= 256 + tab_bytes) {                  // single-pass fp8 (R14)
        unsigned char* tab = (unsigned char*)d_ws + 256;
        ch_cvt8<<<(total8 + 255) / 256, 256, 0, stream>>>(feat, tab, ws, total8);
        ch_main8q<<<blocks, 256, 0, stream>>>(tab, labels, nidx, ws, n);
        ch_finalize<<<1, 1, 0, stream>>>(ws, out);
        return;
    }

    ch_init_ws<<<1, 1, 0, stream>>>(ws);               // f32 direct
    ch_main4f<<<blocks, 256, 0, stream>>>(feat, labels, nidx, ws, n);
    ch_finalize<<<1, 1, 0, stream>>>(ws, out);
}

// Round 16
// 79.400 us; speedup vs baseline: 1.5267x; 1.5267x over previous
//
#include <hip/hip_runtime.h>
#include <hip/hip_fp16.h>

#define KNB 31
#define CH 64
#define TEMP_INV 10.0f   // 1 / temperature(0.1)

typedef _Float16 h2 __attribute__((ext_vector_type(2)));
typedef float f2 __attribute__((ext_vector_type(2)));

// ---------------------------------------------------------------------------
// ws layout:
//   bytes [0, 16)    : double ws[2]  (sum(loss*mask), sum(mask))
//   bytes [256, ...) : fp8 feature table (N*64 B) | fp16 table (N*128 B)
//
// Session lessons baked in:
//  - fp8 e4m3 table (one 64 B line/row): FETCH 167->96.6 MB vs fp16 (R8).
//  - NO __threadfence in hot kernels: per-block device fence = L2 writeback
//    x1563 -> +45% dur at identical FETCH_SIZE (R13 A/B).
//  - Minimal 4-lane online-softmax loop beats every ILP restructure tried
//    (R3/R4/R9/R11/R12) and 2-pass L2 chunking (R15).
//  - ws zeroing folded into cvt8 (saves one launch; R14 == R8 main perf).
// ---------------------------------------------------------------------------

__global__ void ch_init_ws(double* __restrict__ ws, unsigned* __restrict__ ctr) {
    ws[0] = 0.0;
    ws[1] = 0.0;
    *ctr  = 0u;
}

// features f32 -> fp8 e4m3 table (8 floats -> 8 bytes per thread); zeroes ws.
__global__ __launch_bounds__(256) void ch_cvt8(
    const float* __restrict__ in, unsigned char* __restrict__ out,
    double* __restrict__ ws, int total8)
{
    const int idx = blockIdx.x * blockDim.x + threadIdx.x;
    if (idx == 0) { ws[0] = 0.0; ws[1] = 0.0; }
    if (idx >= total8) return;
    const float4* ip = reinterpret_cast<const float4*>(in) + (size_t)idx * 2;
    const float4 a = ip[0];
    const float4 b = ip[1];
    unsigned lo = 0u, hi = 0u;
    lo = __builtin_amdgcn_cvt_pk_fp8_f32(a.x, a.y, lo, false);
    lo = __builtin_amdgcn_cvt_pk_fp8_f32(a.z, a.w, lo, true);
    hi = __builtin_amdgcn_cvt_pk_fp8_f32(b.x, b.y, hi, false);
    hi = __builtin_amdgcn_cvt_pk_fp8_f32(b.z, b.w, hi, true);
    uint2 o; o.x = lo; o.y = hi;
    reinterpret_cast<uint2*>(out)[idx] = o;
}

// fp8 main — R8-exact (proven 69.5 us): 4 lanes/point, lane sub owns 16
// channels (one uint4 = 16 fp8), quad-cooperative 64 B row gathers, online
// softmax. No finalize tail, no fence.
__global__ __launch_bounds__(256) void ch_main8q(
    const unsigned char* __restrict__ tab8,   // (N, 64) fp8 e4m3
    const int*           __restrict__ labels, // (N,)
    const int*           __restrict__ nidx,   // (N, 31)
    double*              __restrict__ ws,
    int n)
{
    const int t   = threadIdx.x;
    const int i   = blockIdx.x * (256 / 4) + (t >> 2);
    const int sub = t & 3;

    float loss_w = 0.0f;
    float pm_f   = 0.0f;

    if (i < n) {
        // own 16 channels: one uint4 of fp8 -> 16 floats in registers
        float fA[16];
        {
            union { uint4 u; unsigned w[4]; } Au;
            Au.u = reinterpret_cast<const uint4*>(tab8 + (size_t)i * CH)[sub];
            #pragma unroll
            for (int q = 0; q < 4; ++q) {
                const f2 p0 = __builtin_amdgcn_cvt_pk_f32_fp8(Au.w[q], false);
                const f2 p1 = __builtin_amdgcn_cvt_pk_f32_fp8(Au.w[q], true);
                fA[4 * q + 0] = p0[0]; fA[4 * q + 1] = p0[1];
                fA[4 * q + 2] = p1[0]; fA[4 * q + 3] = p1[1];
            }
        }

        const int lab = labels[i];
        const int* nrow = nidx + (size_t)i * KNB;

        float m  = -1e30f;  // running max logit
        float se = 0.0f;
        float sp = 0.0f;
        int   cnt = 0;

        #pragma unroll 4
        for (int j = 0; j < KNB; ++j) {
            const int nj = nrow[j];                       // quad-broadcast

            union { uint4 u; unsigned w[4]; } Bu;
            Bu.u = reinterpret_cast<const uint4*>(tab8 + (size_t)nj * CH)[sub];

            float s = 0.0f;
            #pragma unroll
            for (int q = 0; q < 4; ++q) {
                const f2 p0 = __builtin_amdgcn_cvt_pk_f32_fp8(Bu.w[q], false);
                const f2 p1 = __builtin_amdgcn_cvt_pk_f32_fp8(Bu.w[q], true);
                float d;
                d = fA[4 * q + 0] - p0[0]; s = fmaf(d, d, s);
                d = fA[4 * q + 1] - p0[1]; s = fmaf(d, d, s);
                d = fA[4 * q + 2] - p1[0]; s = fmaf(d, d, s);
                d = fA[4 * q + 3] - p1[1]; s = fmaf(d, d, s);
            }
            s += __shfl_xor(s, 1);
            s += __shfl_xor(s, 2);

            const float l = -(sqrtf(s) + 1e-8f);
            const bool pm = (labels[nj] == lab);          // quad-broadcast
            cnt += pm ? 1 : 0;

            if (l > m) {
                const float r = __expf((m - l) * TEMP_INV);
                se *= r;
                sp *= r;
                m = l;
            }
            const float e = __expf((l - m) * TEMP_INV);
            se += e;
            if (pm) sp += e;
        }

        if (sub == 0 && cnt > 0 && cnt < KNB) {
            loss_w = -logf(sp / se + 1e-8f);
            pm_f   = 1.0f;
        }
    }

    __shared__ float s_l[256];
    __shared__ float s_c[256];
    s_l[t] = loss_w;
    s_c[t] = pm_f;
    __syncthreads();
    #pragma unroll
    for (int off = 128; off > 0; off >>= 1) {
        if (t < off) {
            s_l[t] += s_l[t + off];
            s_c[t] += s_c[t + off];
        }
        __syncthreads();
    }
    if (t == 0) {
        atomicAdd(ws,     (double)s_l[0]);
        atomicAdd(ws + 1, (double)s_c[0]);
    }
}

// ---------------------------------------------------------------------------
// Fallback path (R2-exact, proven): fp16 table / f32 direct
// ---------------------------------------------------------------------------
__global__ __launch_bounds__(256) void ch_cvt(
    const float* __restrict__ in, __half* __restrict__ out, int total8)
{
    const int idx = blockIdx.x * blockDim.x + threadIdx.x;
    if (idx >= total8) return;
    const float4* ip = reinterpret_cast<const float4*>(in) + (size_t)idx * 2;
    const float4 a = ip[0];
    const float4 b = ip[1];
    union { uint4 u; __half2 h[4]; } o;
    o.h[0] = __floats2half2_rn(a.x, a.y);
    o.h[1] = __floats2half2_rn(a.z, a.w);
    o.h[2] = __floats2half2_rn(b.x, b.y);
    o.h[3] = __floats2half2_rn(b.z, b.w);
    reinterpret_cast<uint4*>(out)[idx] = o.u;
}

__device__ __forceinline__ float dot2acc(h2 d, float s) {
    return __builtin_amdgcn_fdot2(d, d, s, false);
}

template <bool FP16>
__global__ __launch_bounds__(256) void ch_main4(
    const float*  __restrict__ feat,
    const __half* __restrict__ tab,
    const int*    __restrict__ labels,
    const int*    __restrict__ nidx,
    double*       __restrict__ ws,
    int n)
{
    const int t   = threadIdx.x;
    const int i   = blockIdx.x * (256 / 4) + (t >> 2);
    const int sub = t & 3;

    float loss_w = 0.0f;
    float pm_f   = 0.0f;

    if (i < n) {
        float f[16];
        union { uint4 u[2]; h2 h[8]; } A;
        if constexpr (FP16) {
            const uint4* ap = reinterpret_cast<const uint4*>(tab + (size_t)i * CH + sub * 16);
            A.u[0] = ap[0];
            A.u[1] = ap[1];
        } else {
            const float4* ap = reinterpret_cast<const float4*>(feat + (size_t)i * CH + sub * 16);
            #pragma unroll
            for (int q = 0; q < 4; ++q) {
                const float4 v = ap[q];
                f[4 * q]     = v.x;
                f[4 * q + 1] = v.y;
                f[4 * q + 2] = v.z;
                f[4 * q + 3] = v.w;
            }
        }

        const int lab = labels[i];
        float m = -1e30f, se = 0.0f, sp = 0.0f;
        int cnt = 0;

        #pragma unroll 2
        for (int j = 0; j < KNB; ++j) {
            const int nj = nidx[(size_t)i * KNB + j];

            float s = 0.0f;
            if constexpr (FP16) {
                union { uint4 u[2]; h2 h[8]; } B;
                const uint4* bp = reinterpret_cast<const uint4*>(tab + (size_t)nj * CH + sub * 16);
                B.u[0] = bp[0];
                B.u[1] = bp[1];
                #pragma unroll
                for (int q = 0; q < 8; ++q) {
                    const h2 d = A.h[q] - B.h[q];
                    s = dot2acc(d, s);
                }
            } else {
                const float4* bp = reinterpret_cast<const float4*>(feat + (size_t)nj * CH + sub * 16);
                #pragma unroll
                for (int q = 0; q < 4; ++q) {
                    const float4 v = bp[q];
                    const float dx = f[4 * q]     - v.x;
                    const float dy = f[4 * q + 1] - v.y;
                    const float dz = f[4 * q + 2] - v.z;
                    const float dw = f[4 * q + 3] - v.w;
                    s += dx * dx + dy * dy + dz * dz + dw * dw;
                }
            }
            s += __shfl_xor(s, 1);
            s += __shfl_xor(s, 2);

            const float l = -(sqrtf(s) + 1e-8f);
            const bool pm = (labels[nj] == lab);
            cnt += pm ? 1 : 0;

            if (l > m) {
                const float r = __expf((m - l) * TEMP_INV);
                se *= r; sp *= r; m = l;
            }
            const float e = __expf((l - m) * TEMP_INV);
            se += e;
            if (pm) sp += e;
        }

        if (sub == 0 && cnt > 0 && cnt < KNB) {
            loss_w = -logf(sp / se + 1e-8f);
            pm_f   = 1.0f;
        }
    }

    __shared__ float s_l[256];
    __shared__ float s_c[256];
    s_l[t] = loss_w;
    s_c[t] = pm_f;
    __syncthreads();
    #pragma unroll
    for (int off = 128; off > 0; off >>= 1) {
        if (t < off) {
            s_l[t] += s_l[t + off];
            s_c[t] += s_c[t + off];
        }
        __syncthreads();
    }
    if (t == 0) {
        atomicAdd(ws,     (double)s_l[0]);
        atomicAdd(ws + 1, (double)s_c[0]);
    }
}

__global__ void ch_finalize(const double* __restrict__ ws, float* __restrict__ out) {
    double c = ws[1];
    if (c < 1.0) c = 1.0;
    out[0] = (float)(ws[0] / c);   // WEIGHT = 1.0
}

extern "C" void kernel_launch(void* const* d_in, const int* in_sizes, int n_in,
                              void* d_out, int out_size, void* d_ws, size_t ws_size,
                              hipStream_t stream) {
    const float* feat   = (const float*)d_in[0];
    const int*   labels = (const int*)d_in[1];
    const int*   nidx   = (const int*)d_in[2];
    float*       out    = (float*)d_out;
    double*      ws     = (double*)d_ws;
    unsigned*    ctr    = (unsigned*)((char*)d_ws + 16);

    const int n = in_sizes[1];                 // N = 100000
    const int total8 = n * CH / 8;

    if (ws_size >= 256 + (size_t)n * CH) {              // fp8 table: N*64 B
        unsigned char* tab = (unsigned char*)d_ws + 256;
        ch_cvt8<<<(total8 + 255) / 256, 256, 0, stream>>>(feat, tab, ws, total8);
        const int blocks = (n + 63) / 64;               // 64 points per block
        ch_main8q<<<blocks, 256, 0, stream>>>(tab, labels, nidx, ws, n);
        ch_finalize<<<1, 1, 0, stream>>>(ws, out);
        return;
    }

    ch_init_ws<<<1, 1, 0, stream>>>(ws, ctr);
    const int blocks = (n + 63) / 64;
    if (ws_size >= 256 + (size_t)n * CH * 2) {          // fp16 table
        __half* tab = reinterpret_cast<__half*>((char*)d_ws + 256);
        ch_cvt<<<(total8 + 255) / 256, 256, 0, stream>>>(feat, tab, total8);
        ch_main4<true><<<blocks, 256, 0, stream>>>(feat, tab, labels, nidx, ws, n);
    } else {                                            // f32 direct
        ch_main4<false><<<blocks, 256, 0, stream>>>(feat, nullptr, labels, nidx, ws, n);
    }
    ch_finalize<<<1, 1, 0, stream>>>(ws, out);
}